// Round 14
// baseline (173.994 us; speedup 1.0000x reference)
//
#include <hip/hip_runtime.h>
#include <math.h>

typedef __attribute__((ext_vector_type(8))) short short8;
typedef __attribute__((ext_vector_type(4))) float f32x4;

__device__ __forceinline__ float elu_f(float v) {
    return v > 0.f ? v : __expf(v) - 1.f;
}

__device__ __forceinline__ unsigned short f2bf(float f) {
    unsigned u = __float_as_uint(f);
    unsigned r = (u + 0x7FFF + ((u >> 16) & 1)) >> 16;   // round-to-nearest-even
    return (unsigned short)r;
}

__device__ __forceinline__ float bf2f(unsigned short u) {
    return __uint_as_float(((unsigned)u) << 16);
}

// ---------------- weight precompute ----------------
// blocks 0..255: W1t col b; 256: W1t cols 256..271 = [W1.al1 | W1.ar1]; 257: W2t 18 cols
__global__ __launch_bounds__(256) void prep_kernel(const float* __restrict__ W1,
                                                   const float* __restrict__ al1, const float* __restrict__ ar1,
                                                   const float* __restrict__ W2,
                                                   const float* __restrict__ al2, const float* __restrict__ ar2,
                                                   unsigned short* __restrict__ W1t,
                                                   unsigned short* __restrict__ W2t) {
    int b = blockIdx.x, t = threadIdx.x;
    if (b < 256) {
        W1t[b * 256 + t] = f2bf(W1[t * 256 + b]);
    } else if (b == 256) {
        int k = t;
        #pragma unroll
        for (int h = 0; h < 8; h++) {
            float sl = 0.f, sr = 0.f;
            #pragma unroll
            for (int d = 0; d < 32; d++) {
                float wv = W1[k * 256 + 32 * h + d];
                sl += wv * al1[h * 32 + d];
                sr += wv * ar1[h * 32 + d];
            }
            W1t[(256 + h) * 256 + k] = f2bf(sl);
            W1t[(264 + h) * 256 + k] = f2bf(sr);
        }
    } else {
        int k = t;
        float sl = 0.f, sr = 0.f;
        #pragma unroll
        for (int c = 0; c < 16; c++) {
            float wv = W2[k * 16 + c];
            W2t[c * 256 + k] = f2bf(wv);
            sl += wv * al2[c];
            sr += wv * ar2[c];
        }
        W2t[16 * 256 + k] = f2bf(sl);
        W2t[17 * 256 + k] = f2bf(sr);
    }
}

// ---------------- P1: per-block bucket histogram (bucket = dst >> 10) ----------------
__global__ __launch_bounds__(256) void hist_kernel(const int* __restrict__ dst, int* __restrict__ cntmat,
                                                   int E, int nEB, int nbk) {
    __shared__ int hist[64];
    int b = blockIdx.x, t = threadIdx.x;
    if (t < nbk) hist[t] = 0;
    __syncthreads();
    int e0 = b * 2048 + t * 8;
    #pragma unroll
    for (int i = 0; i < 8; i += 4) {
        int e = e0 + i;
        if (e + 3 < E) {
            int4 d4 = *(const int4*)&dst[e];
            atomicAdd(&hist[d4.x >> 10], 1);
            atomicAdd(&hist[d4.y >> 10], 1);
            atomicAdd(&hist[d4.z >> 10], 1);
            atomicAdd(&hist[d4.w >> 10], 1);
        } else {
            for (int ee = e; ee < E && ee < e + 4; ee++) atomicAdd(&hist[dst[ee] >> 10], 1);
        }
    }
    __syncthreads();
    if (t < nbk) cntmat[t * nEB + b] = hist[t];   // bucket-major layout for flat scan
}

// per-1024-chunk sums (generic flat scan, n arbitrary)
__global__ __launch_bounds__(256) void bsum_kernel(const int* __restrict__ cnt, int* __restrict__ bsum, int n) {
    int b = blockIdx.x, t = threadIdx.x;
    int i0 = b * 1024 + t * 4;
    int s = 0;
    #pragma unroll
    for (int k = 0; k < 4; k++) { int i = i0 + k; if (i < n) s += cnt[i]; }
    #pragma unroll
    for (int m = 1; m < 64; m <<= 1) s += __shfl_xor(s, m);
    __shared__ int ws[4];
    if ((t & 63) == 0) ws[t >> 6] = s;
    __syncthreads();
    if (t == 0) bsum[b] = ws[0] + ws[1] + ws[2] + ws[3];
}

// rescan each 1024-chunk; block-sum prefix recomputed locally (nb <= 64); writes offs[0..n]
__global__ __launch_bounds__(256) void scan_final_kernel(const int* __restrict__ cnt, const int* __restrict__ bsum,
                                                         int* __restrict__ offs, int n, int nb) {
    int b = blockIdx.x, t = threadIdx.x, lane = t & 63, w = t >> 6;
    __shared__ int ws[4];
    __shared__ int bbase_s;
    int i0 = b * 1024 + t * 4;
    int v[4]; int ts = 0;
    #pragma unroll
    for (int k = 0; k < 4; k++) { int i = i0 + k; v[k] = (i < n) ? cnt[i] : 0; ts += v[k]; }
    int x = ts;
    #pragma unroll
    for (int off = 1; off < 64; off <<= 1) {
        int y = __shfl_up(x, off);
        if (lane >= off) x += y;
    }
    if (lane == 63) ws[w] = x;
    if (w == 0) {
        int bv = (lane < nb) ? bsum[lane] : 0;
        int bx = bv;
        #pragma unroll
        for (int off = 1; off < 64; off <<= 1) {
            int y = __shfl_up(bx, off);
            if (lane >= off) bx += y;
        }
        if (lane == b) bbase_s = bx - bv;
    }
    __syncthreads();
    int wbase = 0;
    #pragma unroll
    for (int k = 0; k < 4; k++) if (k < w) wbase += ws[k];
    int base = bbase_s + wbase + (x - ts);
    #pragma unroll
    for (int k = 0; k < 4; k++) {
        int i = i0 + k;
        if (i < n) offs[i] = base;
        base += v[k];
        if (i == n - 1) offs[n] = base;
    }
}

// ---------------- P3: bucket scatter (LDS rank, no global atomics) ----------------
__global__ __launch_bounds__(256) void bucket_scatter_kernel(const int* __restrict__ src,
                                                             const int* __restrict__ dst,
                                                             const int* __restrict__ scanned,
                                                             int2* __restrict__ ebuf,
                                                             int E, int nEB, int nbk) {
    __shared__ int sb[64];
    __shared__ int cur[64];
    int b = blockIdx.x, t = threadIdx.x;
    if (t < nbk) { sb[t] = scanned[t * nEB + b]; cur[t] = 0; }
    __syncthreads();
    int e0 = b * 2048 + t * 8;
    #pragma unroll
    for (int i = 0; i < 8; i += 4) {
        int e = e0 + i;
        if (e + 3 < E) {
            int4 d4 = *(const int4*)&dst[e];
            int4 s4 = *(const int4*)&src[e];
            int k, r;
            k = d4.x >> 10; r = atomicAdd(&cur[k], 1); ebuf[sb[k] + r] = make_int2(d4.x, s4.x);
            k = d4.y >> 10; r = atomicAdd(&cur[k], 1); ebuf[sb[k] + r] = make_int2(d4.y, s4.y);
            k = d4.z >> 10; r = atomicAdd(&cur[k], 1); ebuf[sb[k] + r] = make_int2(d4.z, s4.z);
            k = d4.w >> 10; r = atomicAdd(&cur[k], 1); ebuf[sb[k] + r] = make_int2(d4.w, s4.w);
        } else {
            for (int ee = e; ee < E && ee < e + 4; ee++) {
                int d = dst[ee];
                int k = d >> 10;
                int r = atomicAdd(&cur[k], 1);
                ebuf[sb[k] + r] = make_int2(d, src[ee]);
            }
        }
    }
}

// ---------------- P4: per-bucket CSR finalize (LDS count + scan + cursor scatter) ----------------
__global__ __launch_bounds__(1024) void bucket_csr_kernel(const int2* __restrict__ ebuf,
                                                          const int* __restrict__ scanned,
                                                          int* __restrict__ offs, int* __restrict__ srt,
                                                          int N, int E, int nEB, int nbk) {
    __shared__ int lcnt[1024];
    __shared__ int lcur[1024];
    __shared__ int ws[16];
    int k = blockIdx.x, t = threadIdx.x;
    int lane = t & 63, w = t >> 6;
    int eb = scanned[k * nEB];
    int ee = (k + 1 < nbk) ? scanned[(k + 1) * nEB] : E;
    lcnt[t] = 0;
    __syncthreads();
    for (int e = eb + t; e < ee; e += 1024) {
        int2 p = ebuf[e];
        atomicAdd(&lcnt[p.x & 1023], 1);
    }
    __syncthreads();
    int v = lcnt[t];
    int x = v;
    #pragma unroll
    for (int off = 1; off < 64; off <<= 1) {
        int y = __shfl_up(x, off);
        if (lane >= off) x += y;
    }
    if (lane == 63) ws[w] = x;
    __syncthreads();
    if (w == 0) {
        int wv = (lane < 16) ? ws[lane] : 0;
        int wx = wv;
        #pragma unroll
        for (int off = 1; off < 16; off <<= 1) {
            int y = __shfl_up(wx, off);
            if (lane >= off) wx += y;
        }
        if (lane < 16) ws[lane] = wx - wv;   // exclusive wave bases
    }
    __syncthreads();
    int excl = ws[w] + (x - v);
    int node = (k << 10) + t;
    if (node < N) offs[node] = eb + excl;
    if (k == nbk - 1 && t == 0) offs[N] = E;
    lcur[t] = eb + excl;
    __syncthreads();
    for (int e = eb + t; e < ee; e += 1024) {
        int2 p = ebuf[e];
        int pos = atomicAdd(&lcur[p.x & 1023], 1);
        srt[pos] = p.y;
    }
}

// ---------------- GEMM1: [h1 | el1 | er1] = x @ [W1 | wl | wr] via bf16 MFMA ----------------
#define STR1 40
__global__ __launch_bounds__(512) void gemm1_mfma(const float* __restrict__ x,
                                                  const unsigned short* __restrict__ W1t,
                                                  unsigned short* __restrict__ h,
                                                  float* __restrict__ el1, float* __restrict__ er1, int n) {
    __shared__ unsigned short As[128 * STR1];
    __shared__ unsigned short Bs[272 * STR1];
    int t = threadIdx.x;
    int w = t >> 6, l = t & 63;
    int rb = blockIdx.x * 128;
    f32x4 acc[17] = {};
    int ar = t >> 2;          // A-stage row 0..127
    int ak = (t & 3) * 8;     // A-stage k0
    int lr = w * 16 + (l & 15);
    int lg = l >> 4;
    for (int kc = 0; kc < 256; kc += 32) {
        {   // stage A (128x32), fp32 -> bf16
            int gr = rb + ar;
            float v[8];
            if (gr < n) {
                f32x4 v0 = *(const f32x4*)&x[(size_t)gr * 256 + kc + ak];
                f32x4 v1 = *(const f32x4*)&x[(size_t)gr * 256 + kc + ak + 4];
                v[0] = v0.x; v[1] = v0.y; v[2] = v0.z; v[3] = v0.w;
                v[4] = v1.x; v[5] = v1.y; v[6] = v1.z; v[7] = v1.w;
            } else {
                #pragma unroll
                for (int i = 0; i < 8; i++) v[i] = 0.f;
            }
            short8 bv;
            #pragma unroll
            for (int i = 0; i < 8; i++) bv[i] = (short)f2bf(v[i]);
            *(short8*)&As[ar * STR1 + ak] = bv;
        }
        #pragma unroll
        for (int i = 0; i < 3; i++) {   // stage B: 272 cols x 4 chunks = 1088
            int idx = t + i * 512;
            if (idx < 1088) {
                int bn = idx >> 2;
                int bk = (idx & 3) * 8;
                short8 bv = *(const short8*)&W1t[(size_t)bn * 256 + kc + bk];
                *(short8*)&Bs[bn * STR1 + bk] = bv;
            }
        }
        __syncthreads();
        short8 a = *(short8*)&As[lr * STR1 + lg * 8];
        #pragma unroll
        for (int j = 0; j < 17; j++) {
            short8 bfrag = *(short8*)&Bs[(j * 16 + (l & 15)) * STR1 + lg * 8];
            acc[j] = __builtin_amdgcn_mfma_f32_16x16x32_bf16(a, bfrag, acc[j], 0, 0, 0);
        }
        __syncthreads();
    }
    int r0 = rb + w * 16 + 4 * (l >> 4);
    int c0 = l & 15;
    #pragma unroll
    for (int j = 0; j < 16; j++) {
        #pragma unroll
        for (int i = 0; i < 4; i++) {
            int gr = r0 + i;
            if (gr < n) h[(size_t)gr * 256 + j * 16 + c0] = f2bf(acc[j][i]);
        }
    }
    #pragma unroll
    for (int i = 0; i < 4; i++) {       // j=16: cols 256..271 = [el(8) | er(8)]
        int gr = r0 + i;
        if (gr < n) {
            if (c0 < 8) el1[gr * 8 + c0] = acc[16][i];
            else        er1[gr * 8 + (c0 - 8)] = acc[16][i];
        }
    }
}

// ---------------- FUSED layer-1 aggregation + bias + ELU + layer-2 linear ----------------
// per node-wave: softmax-weighted gather into acc (fp32, 8 dims/lane x 32 lanes),
// then [h2 | el2 | er2] = x1_row @ W2t via in-register matvec + butterfly reduce.
// Matvec done in 3 rounds of 6 outputs to cap register pressure.
__global__ __launch_bounds__(256) void agg1_fused_kernel(const unsigned short* __restrict__ h1b,
                                                         const float* __restrict__ el1,
                                                         const float* __restrict__ er1,
                                                         const float* __restrict__ b1,
                                                         const unsigned short* __restrict__ W2t,
                                                         const int* __restrict__ offs, const int* __restrict__ srt,
                                                         float* __restrict__ h2, float* __restrict__ el2,
                                                         float* __restrict__ er2, int n) {
    int t = threadIdx.x; int lane = t & 63;
    int node = blockIdx.x * 4 + (t >> 6);
    if (node >= n) return;
    int beg = offs[node], end = offs[node + 1];
    int q = lane & 31;          // dim-group: dims [8q, 8q+8)
    int head = q >> 2;
    int half = lane >> 5;
    float er_h = er1[node * 8 + head];
    float acc[8] = {};
    float dsum = 0.f;
    for (int e = beg + half; e < end; e += 8) {
        int eB = e + 2, eC = e + 4, eD = e + 6;
        bool hB = eB < end, hC = eC < end, hD = eD < end;
        int sA = srt[e];
        int sB = srt[hB ? eB : e];
        int sC = srt[hC ? eC : e];
        int sD = srt[hD ? eD : e];
        float exA = __expf(el1[sA * 8 + head] + er_h);          // leaky slope 1.0 == identity
        float exB = hB ? __expf(el1[sB * 8 + head] + er_h) : 0.f;
        float exC = hC ? __expf(el1[sC * 8 + head] + er_h) : 0.f;
        float exD = hD ? __expf(el1[sD * 8 + head] + er_h) : 0.f;
        short8 hA = *(const short8*)&h1b[(size_t)sA * 256 + q * 8];
        short8 hBv = *(const short8*)&h1b[(size_t)sB * 256 + q * 8];
        short8 hCv = *(const short8*)&h1b[(size_t)sC * 256 + q * 8];
        short8 hDv = *(const short8*)&h1b[(size_t)sD * 256 + q * 8];
        dsum += (exA + exB) + (exC + exD);
        #pragma unroll
        for (int k = 0; k < 8; k++)
            acc[k] += exA * bf2f((unsigned short)hA[k]) + exB * bf2f((unsigned short)hBv[k])
                    + exC * bf2f((unsigned short)hCv[k]) + exD * bf2f((unsigned short)hDv[k]);
    }
    dsum += __shfl_xor(dsum, 32);
    #pragma unroll
    for (int k = 0; k < 8; k++) acc[k] += __shfl_xor(acc[k], 32);
    // x1 row segment in registers (all 64 lanes; halves redundant)
    float inv = dsum > 0.f ? 1.f / dsum : 0.f;
    f32x4 b0 = *(const f32x4*)&b1[q * 8];
    f32x4 b4 = *(const f32x4*)&b1[q * 8 + 4];
    float o[8];
    o[0] = elu_f(acc[0] * inv + b0.x); o[1] = elu_f(acc[1] * inv + b0.y);
    o[2] = elu_f(acc[2] * inv + b0.z); o[3] = elu_f(acc[3] * inv + b0.w);
    o[4] = elu_f(acc[4] * inv + b4.x); o[5] = elu_f(acc[5] * inv + b4.y);
    o[6] = elu_f(acc[6] * inv + b4.z); o[7] = elu_f(acc[7] * inv + b4.w);
    // fused layer-2 linear: 18 outputs (h2[16] | el2 | er2), 3 rounds of 6
    float outv = 0.f;
    #pragma unroll
    for (int g = 0; g < 3; g++) {
        float part[6];
        #pragma unroll
        for (int c = 0; c < 6; c++) {
            short8 wv = *(const short8*)&W2t[(g * 6 + c) * 256 + q * 8];
            float s = 0.f;
            #pragma unroll
            for (int j = 0; j < 8; j++) s += o[j] * bf2f((unsigned short)wv[j]);
            part[c] = s;
        }
        #pragma unroll
        for (int mask = 1; mask < 32; mask <<= 1) {
            #pragma unroll
            for (int c = 0; c < 6; c++) part[c] += __shfl_xor(part[c], mask);
        }
        #pragma unroll
        for (int c = 0; c < 6; c++) if (q == g * 6 + c) outv = part[c];
    }
    if (half == 0) {
        if (q < 16) h2[(size_t)node * 16 + q] = outv;
        else if (q == 16) el2[node] = outv;
        else if (q == 17) er2[node] = outv;
    }
}

// ---------------- layer-2 aggregation + bias + ELU -> out ----------------
__global__ __launch_bounds__(256) void agg2_kernel(const float* __restrict__ h2,
                                                   const float* __restrict__ el2,
                                                   const float* __restrict__ er2, const float* __restrict__ b2,
                                                   const int* __restrict__ offs, const int* __restrict__ srt,
                                                   float* __restrict__ out, int n) {
    int t = threadIdx.x; int lane = t & 63;
    int node = blockIdx.x * 4 + (t >> 6);
    if (node >= n) return;
    int beg = offs[node], end = offs[node + 1];
    int dim = lane & 15, eg = lane >> 4;
    float er_n = er2[node];
    float acc = 0.f, dsum = 0.f;
    for (int e = beg + eg; e < end; e += 16) {
        int eB = e + 4, eC = e + 8, eD = e + 12;
        bool hB = eB < end, hC = eC < end, hD = eD < end;
        int sA = srt[e];
        int sB = srt[hB ? eB : e];
        int sC = srt[hC ? eC : e];
        int sD = srt[hD ? eD : e];
        float evA = el2[sA] + er_n; evA = fmaxf(evA, 0.2f * evA);
        float evB = el2[sB] + er_n; evB = fmaxf(evB, 0.2f * evB);
        float evC = el2[sC] + er_n; evC = fmaxf(evC, 0.2f * evC);
        float evD = el2[sD] + er_n; evD = fmaxf(evD, 0.2f * evD);
        float exA = __expf(evA);
        float exB = hB ? __expf(evB) : 0.f;
        float exC = hC ? __expf(evC) : 0.f;
        float exD = hD ? __expf(evD) : 0.f;
        float hA = h2[(size_t)sA * 16 + dim];
        float hBv = h2[(size_t)sB * 16 + dim];
        float hCv = h2[(size_t)sC * 16 + dim];
        float hDv = h2[(size_t)sD * 16 + dim];
        dsum += (exA + exB) + (exC + exD);
        acc += exA * hA + exB * hBv + exC * hCv + exD * hDv;
    }
    acc += __shfl_xor(acc, 16); acc += __shfl_xor(acc, 32);
    dsum += __shfl_xor(dsum, 16); dsum += __shfl_xor(dsum, 32);
    float inv = dsum > 0.f ? 1.f / dsum : 0.f;
    float o = elu_f(acc * inv + b2[dim]);
    if (lane < 16) out[(size_t)node * 16 + dim] = o;
}

extern "C" void kernel_launch(void* const* d_in, const int* in_sizes, int n_in,
                              void* d_out, int out_size, void* d_ws, size_t ws_size,
                              hipStream_t stream) {
    const float* x   = (const float*)d_in[0];
    const int*   src = (const int*)d_in[1];
    const int*   dst = (const int*)d_in[2];
    const float* W1  = (const float*)d_in[3];
    const float* al1 = (const float*)d_in[4];
    const float* ar1 = (const float*)d_in[5];
    const float* b1  = (const float*)d_in[6];
    const float* W2  = (const float*)d_in[7];
    const float* al2 = (const float*)d_in[8];
    const float* ar2 = (const float*)d_in[9];
    const float* b2  = (const float*)d_in[10];
    const int N = in_sizes[0] / 256;
    const int E = in_sizes[1];

    char* wsp = (char*)d_ws;
    size_t off = 0;
    auto alloc = [&](size_t bytes) -> void* {
        void* p = wsp + off;
        off = (off + bytes + 255) & ~(size_t)255;
        return p;
    };
    unsigned short* h1b = (unsigned short*)alloc((size_t)N * 256 * 2);
    float* el1 = (float*)alloc((size_t)N * 8 * 4);
    float* er1 = (float*)alloc((size_t)N * 8 * 4);
    float* h2  = (float*)alloc((size_t)N * 16 * 4);
    float* el2 = (float*)alloc((size_t)N * 4);
    float* er2 = (float*)alloc((size_t)N * 4);
    int*   offs = (int*)alloc((size_t)(N + 1) * 4);
    int*   srt  = (int*)alloc((size_t)E * 4);
    int2*  ebuf = (int2*)alloc((size_t)E * 8);
    unsigned short* W1t = (unsigned short*)alloc((size_t)272 * 256 * 2);
    unsigned short* W2t = (unsigned short*)alloc((size_t)18 * 256 * 2);

    const int nEB = (E + 2047) / 2048;       // edge blocks (2048 edges each)
    const int nbk = (N + 1023) >> 10;        // buckets (1024 nodes each)
    const int n2  = nbk * nEB;               // flat (bucket, block) count matrix
    const int NB2 = (n2 + 1023) / 1024;      // scan chunks (<= 64)

    int* cntmat  = (int*)alloc((size_t)n2 * 4);
    int* scanned = (int*)alloc((size_t)(n2 + 1) * 4);
    int* bsum    = (int*)alloc((size_t)64 * 4);

    prep_kernel<<<258, 256, 0, stream>>>(W1, al1, ar1, W2, al2, ar2, W1t, W2t);
    hist_kernel<<<nEB, 256, 0, stream>>>(dst, cntmat, E, nEB, nbk);
    bsum_kernel<<<NB2, 256, 0, stream>>>(cntmat, bsum, n2);
    scan_final_kernel<<<NB2, 256, 0, stream>>>(cntmat, bsum, scanned, n2, NB2);
    bucket_scatter_kernel<<<nEB, 256, 0, stream>>>(src, dst, scanned, ebuf, E, nEB, nbk);
    bucket_csr_kernel<<<nbk, 1024, 0, stream>>>(ebuf, scanned, offs, srt, N, E, nEB, nbk);

    gemm1_mfma<<<(N + 127) / 128, 512, 0, stream>>>(x, W1t, h1b, el1, er1, N);
    agg1_fused_kernel<<<(N + 3) / 4, 256, 0, stream>>>(h1b, el1, er1, b1, W2t, offs, srt,
                                                       h2, el2, er2, N);
    agg2_kernel<<<(N + 3) / 4, 256, 0, stream>>>(h2, el2, er2, b2, offs, srt, (float*)d_out, N);
}

// Round 15
// 173.976 us; speedup vs baseline: 1.0001x; 1.0001x over previous
//
#include <hip/hip_runtime.h>
#include <math.h>

typedef __attribute__((ext_vector_type(8))) short short8;
typedef __attribute__((ext_vector_type(4))) float f32x4;

__device__ __forceinline__ float elu_f(float v) {
    return v > 0.f ? v : __expf(v) - 1.f;
}

__device__ __forceinline__ unsigned short f2bf(float f) {
    unsigned u = __float_as_uint(f);
    unsigned r = (u + 0x7FFF + ((u >> 16) & 1)) >> 16;   // round-to-nearest-even
    return (unsigned short)r;
}

__device__ __forceinline__ float bf2f(unsigned short u) {
    return __uint_as_float(((unsigned)u) << 16);
}

// ---------------- FUSED: bucket histogram + weight precompute (independent work) ----------------
// blocks [0,nEB): hist (2048 edges, LDS atomics); [nEB,nEB+256): W1t col; nEB+256: wl/wr; nEB+257: W2t
__global__ __launch_bounds__(256) void prep_hist_kernel(const int* __restrict__ dst, int* __restrict__ cntmat,
                                                        int E, int nEB, int nbk,
                                                        const float* __restrict__ W1,
                                                        const float* __restrict__ al1, const float* __restrict__ ar1,
                                                        const float* __restrict__ W2,
                                                        const float* __restrict__ al2, const float* __restrict__ ar2,
                                                        unsigned short* __restrict__ W1t,
                                                        unsigned short* __restrict__ W2t) {
    __shared__ int hist[64];
    int b = blockIdx.x, t = threadIdx.x;
    if (b < nEB) {
        if (t < nbk) hist[t] = 0;
        __syncthreads();
        int e0 = b * 2048 + t * 8;
        #pragma unroll
        for (int i = 0; i < 8; i += 4) {
            int e = e0 + i;
            if (e + 3 < E) {
                int4 d4 = *(const int4*)&dst[e];
                atomicAdd(&hist[d4.x >> 10], 1);
                atomicAdd(&hist[d4.y >> 10], 1);
                atomicAdd(&hist[d4.z >> 10], 1);
                atomicAdd(&hist[d4.w >> 10], 1);
            } else {
                for (int ee = e; ee < E && ee < e + 4; ee++) atomicAdd(&hist[dst[ee] >> 10], 1);
            }
        }
        __syncthreads();
        if (t < nbk) cntmat[t * nEB + b] = hist[t];   // bucket-major for flat scan
        return;
    }
    int bb = b - nEB;
    if (bb < 256) {
        W1t[bb * 256 + t] = f2bf(W1[t * 256 + bb]);
    } else if (bb == 256) {
        int k = t;
        #pragma unroll
        for (int h = 0; h < 8; h++) {
            float sl = 0.f, sr = 0.f;
            #pragma unroll
            for (int d = 0; d < 32; d++) {
                float wv = W1[k * 256 + 32 * h + d];
                sl += wv * al1[h * 32 + d];
                sr += wv * ar1[h * 32 + d];
            }
            W1t[(256 + h) * 256 + k] = f2bf(sl);
            W1t[(264 + h) * 256 + k] = f2bf(sr);
        }
    } else {
        int k = t;
        float sl = 0.f, sr = 0.f;
        #pragma unroll
        for (int c = 0; c < 16; c++) {
            float wv = W2[k * 16 + c];
            W2t[c * 256 + k] = f2bf(wv);
            sl += wv * al2[c];
            sr += wv * ar2[c];
        }
        W2t[16 * 256 + k] = f2bf(sl);
        W2t[17 * 256 + k] = f2bf(sr);
        #pragma unroll
        for (int c = 18; c < 32; c++) W2t[c * 256 + k] = 0;
    }
}

// per-1024-chunk sums (generic flat scan)
__global__ __launch_bounds__(256) void bsum_kernel(const int* __restrict__ cnt, int* __restrict__ bsum, int n) {
    int b = blockIdx.x, t = threadIdx.x;
    int i0 = b * 1024 + t * 4;
    int s = 0;
    #pragma unroll
    for (int k = 0; k < 4; k++) { int i = i0 + k; if (i < n) s += cnt[i]; }
    #pragma unroll
    for (int m = 1; m < 64; m <<= 1) s += __shfl_xor(s, m);
    __shared__ int ws[4];
    if ((t & 63) == 0) ws[t >> 6] = s;
    __syncthreads();
    if (t == 0) bsum[b] = ws[0] + ws[1] + ws[2] + ws[3];
}

// rescan each 1024-chunk; block-sum prefix recomputed locally (nb <= 64); writes offs[0..n]
__global__ __launch_bounds__(256) void scan_final_kernel(const int* __restrict__ cnt, const int* __restrict__ bsum,
                                                         int* __restrict__ offs, int n, int nb) {
    int b = blockIdx.x, t = threadIdx.x, lane = t & 63, w = t >> 6;
    __shared__ int ws[4];
    __shared__ int bbase_s;
    int i0 = b * 1024 + t * 4;
    int v[4]; int ts = 0;
    #pragma unroll
    for (int k = 0; k < 4; k++) { int i = i0 + k; v[k] = (i < n) ? cnt[i] : 0; ts += v[k]; }
    int x = ts;
    #pragma unroll
    for (int off = 1; off < 64; off <<= 1) {
        int y = __shfl_up(x, off);
        if (lane >= off) x += y;
    }
    if (lane == 63) ws[w] = x;
    if (w == 0) {
        int bv = (lane < nb) ? bsum[lane] : 0;
        int bx = bv;
        #pragma unroll
        for (int off = 1; off < 64; off <<= 1) {
            int y = __shfl_up(bx, off);
            if (lane >= off) bx += y;
        }
        if (lane == b) bbase_s = bx - bv;
    }
    __syncthreads();
    int wbase = 0;
    #pragma unroll
    for (int k = 0; k < 4; k++) if (k < w) wbase += ws[k];
    int base = bbase_s + wbase + (x - ts);
    #pragma unroll
    for (int k = 0; k < 4; k++) {
        int i = i0 + k;
        if (i < n) offs[i] = base;
        base += v[k];
        if (i == n - 1) offs[n] = base;
    }
}

// ---------------- FUSED: bucket scatter (LDS rank) + GEMM1 MFMA (independent work) ----------------
// parity-interleaved blocks: even -> scatter (2048 edges, 512 thr x 4), odd -> gemm (128-row tile).
#define STR1 40
__global__ __launch_bounds__(512) void scatter_gemm1_kernel(const int* __restrict__ src,
                                                            const int* __restrict__ dst,
                                                            const int* __restrict__ scanned,
                                                            int2* __restrict__ ebuf,
                                                            int E, int nEB, int nbk,
                                                            const float* __restrict__ x,
                                                            const unsigned short* __restrict__ W1t,
                                                            unsigned short* __restrict__ h,
                                                            float* __restrict__ el1, float* __restrict__ er1,
                                                            int n, int nGB) {
    __shared__ unsigned short As[128 * STR1];
    __shared__ unsigned short Bs[272 * STR1];
    __shared__ int sb[64];
    __shared__ int cur[64];
    int b = blockIdx.x, t = threadIdx.x;
    int nPair = (nEB < nGB) ? nEB : nGB;
    int type, id;
    if (b < 2 * nPair) { type = b & 1; id = b >> 1; }
    else {
        int r = b - 2 * nPair;
        if (nEB > nGB) { type = 0; id = nPair + r; }
        else           { type = 1; id = nPair + r; }
    }
    if (type == 0) {
        // ---- scatter block: 512 thr x 4 edges = 2048 (matches hist segmentation) ----
        if (t < nbk) { sb[t] = scanned[t * nEB + id]; cur[t] = 0; }
        __syncthreads();
        int e0 = id * 2048 + t * 4;
        if (e0 + 3 < E) {
            int4 d4 = *(const int4*)&dst[e0];
            int4 s4 = *(const int4*)&src[e0];
            int k, r;
            k = d4.x >> 10; r = atomicAdd(&cur[k], 1); ebuf[sb[k] + r] = make_int2(d4.x, s4.x);
            k = d4.y >> 10; r = atomicAdd(&cur[k], 1); ebuf[sb[k] + r] = make_int2(d4.y, s4.y);
            k = d4.z >> 10; r = atomicAdd(&cur[k], 1); ebuf[sb[k] + r] = make_int2(d4.z, s4.z);
            k = d4.w >> 10; r = atomicAdd(&cur[k], 1); ebuf[sb[k] + r] = make_int2(d4.w, s4.w);
        } else {
            for (int ee = e0; ee < E && ee < e0 + 4; ee++) {
                int d = dst[ee];
                int k = d >> 10;
                int r = atomicAdd(&cur[k], 1);
                ebuf[sb[k] + r] = make_int2(d, src[ee]);
            }
        }
        return;
    }
    // ---- gemm block: [h1 | el1 | er1] tile ----
    int w = t >> 6, l = t & 63;
    int rb = id * 128;
    f32x4 acc[17] = {};
    int ar = t >> 2;
    int ak = (t & 3) * 8;
    int lr = w * 16 + (l & 15);
    int lg = l >> 4;
    for (int kc = 0; kc < 256; kc += 32) {
        {   // stage A (128x32), fp32 -> bf16
            int gr = rb + ar;
            float v[8];
            if (gr < n) {
                f32x4 v0 = *(const f32x4*)&x[(size_t)gr * 256 + kc + ak];
                f32x4 v1 = *(const f32x4*)&x[(size_t)gr * 256 + kc + ak + 4];
                v[0] = v0.x; v[1] = v0.y; v[2] = v0.z; v[3] = v0.w;
                v[4] = v1.x; v[5] = v1.y; v[6] = v1.z; v[7] = v1.w;
            } else {
                #pragma unroll
                for (int i = 0; i < 8; i++) v[i] = 0.f;
            }
            short8 bv;
            #pragma unroll
            for (int i = 0; i < 8; i++) bv[i] = (short)f2bf(v[i]);
            *(short8*)&As[ar * STR1 + ak] = bv;
        }
        #pragma unroll
        for (int i = 0; i < 3; i++) {   // stage B: 272 cols x 4 chunks = 1088
            int idx = t + i * 512;
            if (idx < 1088) {
                int bn = idx >> 2;
                int bk = (idx & 3) * 8;
                short8 bv = *(const short8*)&W1t[(size_t)bn * 256 + kc + bk];
                *(short8*)&Bs[bn * STR1 + bk] = bv;
            }
        }
        __syncthreads();
        short8 a = *(short8*)&As[lr * STR1 + lg * 8];
        #pragma unroll
        for (int j = 0; j < 17; j++) {
            short8 bfrag = *(short8*)&Bs[(j * 16 + (l & 15)) * STR1 + lg * 8];
            acc[j] = __builtin_amdgcn_mfma_f32_16x16x32_bf16(a, bfrag, acc[j], 0, 0, 0);
        }
        __syncthreads();
    }
    int r0 = rb + w * 16 + 4 * (l >> 4);
    int c0 = l & 15;
    #pragma unroll
    for (int j = 0; j < 16; j++) {
        #pragma unroll
        for (int i = 0; i < 4; i++) {
            int gr = r0 + i;
            if (gr < n) h[(size_t)gr * 256 + j * 16 + c0] = f2bf(acc[j][i]);
        }
    }
    #pragma unroll
    for (int i = 0; i < 4; i++) {       // j=16: cols 256..271 = [el(8) | er(8)]
        int gr = r0 + i;
        if (gr < n) {
            if (c0 < 8) el1[gr * 8 + c0] = acc[16][i];
            else        er1[gr * 8 + (c0 - 8)] = acc[16][i];
        }
    }
}

// ---------------- P4: per-bucket CSR finalize (LDS count + scan + cursor scatter) ----------------
__global__ __launch_bounds__(1024) void bucket_csr_kernel(const int2* __restrict__ ebuf,
                                                          const int* __restrict__ scanned,
                                                          int* __restrict__ offs, int* __restrict__ srt,
                                                          int N, int E, int nEB, int nbk) {
    __shared__ int lcnt[1024];
    __shared__ int lcur[1024];
    __shared__ int ws[16];
    int k = blockIdx.x, t = threadIdx.x;
    int lane = t & 63, w = t >> 6;
    int eb = scanned[k * nEB];
    int ee = (k + 1 < nbk) ? scanned[(k + 1) * nEB] : E;
    lcnt[t] = 0;
    __syncthreads();
    for (int e = eb + t; e < ee; e += 1024) {
        int2 p = ebuf[e];
        atomicAdd(&lcnt[p.x & 1023], 1);
    }
    __syncthreads();
    int v = lcnt[t];
    int x = v;
    #pragma unroll
    for (int off = 1; off < 64; off <<= 1) {
        int y = __shfl_up(x, off);
        if (lane >= off) x += y;
    }
    if (lane == 63) ws[w] = x;
    __syncthreads();
    if (w == 0) {
        int wv = (lane < 16) ? ws[lane] : 0;
        int wx = wv;
        #pragma unroll
        for (int off = 1; off < 16; off <<= 1) {
            int y = __shfl_up(wx, off);
            if (lane >= off) wx += y;
        }
        if (lane < 16) ws[lane] = wx - wv;   // exclusive wave bases
    }
    __syncthreads();
    int excl = ws[w] + (x - v);
    int node = (k << 10) + t;
    if (node < N) offs[node] = eb + excl;
    if (k == nbk - 1 && t == 0) offs[N] = E;
    lcur[t] = eb + excl;
    __syncthreads();
    for (int e = eb + t; e < ee; e += 1024) {
        int2 p = ebuf[e];
        int pos = atomicAdd(&lcur[p.x & 1023], 1);
        srt[pos] = p.y;
    }
}

// ---------------- layer-1 aggregation + bias + ELU -> x1 (bf16) ----------------
__global__ __launch_bounds__(256) void agg1_kernel(const unsigned short* __restrict__ h1b,
                                                   const float* __restrict__ el1,
                                                   const float* __restrict__ er1, const float* __restrict__ b1,
                                                   const int* __restrict__ offs, const int* __restrict__ srt,
                                                   unsigned short* __restrict__ x1b, int n) {
    int t = threadIdx.x; int lane = t & 63;
    int node = blockIdx.x * 4 + (t >> 6);
    if (node >= n) return;
    int beg = offs[node], end = offs[node + 1];
    int q = lane & 31;          // dim-group: dims [8q, 8q+8)
    int head = q >> 2;
    int half = lane >> 5;
    float er_h = er1[node * 8 + head];
    float acc[8] = {};
    float dsum = 0.f;
    for (int e = beg + half; e < end; e += 8) {
        int eB = e + 2, eC = e + 4, eD = e + 6;
        bool hB = eB < end, hC = eC < end, hD = eD < end;
        int sA = srt[e];
        int sB = srt[hB ? eB : e];
        int sC = srt[hC ? eC : e];
        int sD = srt[hD ? eD : e];
        float exA = __expf(el1[sA * 8 + head] + er_h);          // leaky slope 1.0 == identity
        float exB = hB ? __expf(el1[sB * 8 + head] + er_h) : 0.f;
        float exC = hC ? __expf(el1[sC * 8 + head] + er_h) : 0.f;
        float exD = hD ? __expf(el1[sD * 8 + head] + er_h) : 0.f;
        short8 hA = *(const short8*)&h1b[(size_t)sA * 256 + q * 8];
        short8 hBv = *(const short8*)&h1b[(size_t)sB * 256 + q * 8];
        short8 hCv = *(const short8*)&h1b[(size_t)sC * 256 + q * 8];
        short8 hDv = *(const short8*)&h1b[(size_t)sD * 256 + q * 8];
        dsum += (exA + exB) + (exC + exD);
        #pragma unroll
        for (int k = 0; k < 8; k++)
            acc[k] += exA * bf2f((unsigned short)hA[k]) + exB * bf2f((unsigned short)hBv[k])
                    + exC * bf2f((unsigned short)hCv[k]) + exD * bf2f((unsigned short)hDv[k]);
    }
    dsum += __shfl_xor(dsum, 32);
    #pragma unroll
    for (int k = 0; k < 8; k++) acc[k] += __shfl_xor(acc[k], 32);
    if (half == 0) {
        float inv = dsum > 0.f ? 1.f / dsum : 0.f;
        f32x4 b0 = *(const f32x4*)&b1[q * 8];
        f32x4 b4 = *(const f32x4*)&b1[q * 8 + 4];
        float o[8];
        o[0] = elu_f(acc[0] * inv + b0.x); o[1] = elu_f(acc[1] * inv + b0.y);
        o[2] = elu_f(acc[2] * inv + b0.z); o[3] = elu_f(acc[3] * inv + b0.w);
        o[4] = elu_f(acc[4] * inv + b4.x); o[5] = elu_f(acc[5] * inv + b4.y);
        o[6] = elu_f(acc[6] * inv + b4.z); o[7] = elu_f(acc[7] * inv + b4.w);
        short8 ov;
        #pragma unroll
        for (int k = 0; k < 8; k++) ov[k] = (short)f2bf(o[k]);
        *(short8*)&x1b[(size_t)node * 256 + q * 8] = ov;
    }
}

// ---------------- GEMM2: [h2 | el2 | er2] = x1 @ [W2 | wl2 | wr2] via bf16 MFMA; h2 fp32 ----------------
__global__ __launch_bounds__(256) void gemm2_mfma(const unsigned short* __restrict__ x1b,
                                                  const unsigned short* __restrict__ W2t,
                                                  float* __restrict__ h2, float* __restrict__ el2,
                                                  float* __restrict__ er2, int n) {
    __shared__ unsigned short As[64 * STR1];
    __shared__ unsigned short Bs[32 * STR1];
    int t = threadIdx.x;
    int w = t >> 6, l = t & 63;
    int rb = blockIdx.x * 64;
    f32x4 acc[2] = {};
    int ar = t >> 2;
    int ak = (t & 3) * 8;
    int lr = w * 16 + (l & 15);
    int lg = l >> 4;
    for (int kc = 0; kc < 256; kc += 32) {
        {
            int gr = rb + ar;
            short8 av = {0, 0, 0, 0, 0, 0, 0, 0};
            if (gr < n) av = *(const short8*)&x1b[(size_t)gr * 256 + kc + ak];
            *(short8*)&As[ar * STR1 + ak] = av;
        }
        if (t < 128) {   // 32 cols x 4 chunks
            int bn = t >> 2, bk = (t & 3) * 8;
            short8 bv = *(const short8*)&W2t[(size_t)bn * 256 + kc + bk];
            *(short8*)&Bs[bn * STR1 + bk] = bv;
        }
        __syncthreads();
        short8 a = *(short8*)&As[lr * STR1 + lg * 8];
        #pragma unroll
        for (int j = 0; j < 2; j++) {
            short8 bfrag = *(short8*)&Bs[(j * 16 + (l & 15)) * STR1 + lg * 8];
            acc[j] = __builtin_amdgcn_mfma_f32_16x16x32_bf16(a, bfrag, acc[j], 0, 0, 0);
        }
        __syncthreads();
    }
    int r0 = rb + w * 16 + 4 * (l >> 4);
    int c0 = l & 15;
    #pragma unroll
    for (int i = 0; i < 4; i++) {
        int gr = r0 + i;
        if (gr < n) {
            h2[(size_t)gr * 16 + c0] = acc[0][i];
            if (c0 == 0) el2[gr] = acc[1][i];        // col 16
            else if (c0 == 1) er2[gr] = acc[1][i];   // col 17
        }
    }
}

// ---------------- layer-2 aggregation + bias + ELU -> out ----------------
__global__ __launch_bounds__(256) void agg2_kernel(const float* __restrict__ h2,
                                                   const float* __restrict__ el2,
                                                   const float* __restrict__ er2, const float* __restrict__ b2,
                                                   const int* __restrict__ offs, const int* __restrict__ srt,
                                                   float* __restrict__ out, int n) {
    int t = threadIdx.x; int lane = t & 63;
    int node = blockIdx.x * 4 + (t >> 6);
    if (node >= n) return;
    int beg = offs[node], end = offs[node + 1];
    int dim = lane & 15, eg = lane >> 4;
    float er_n = er2[node];
    float acc = 0.f, dsum = 0.f;
    for (int e = beg + eg; e < end; e += 16) {
        int eB = e + 4, eC = e + 8, eD = e + 12;
        bool hB = eB < end, hC = eC < end, hD = eD < end;
        int sA = srt[e];
        int sB = srt[hB ? eB : e];
        int sC = srt[hC ? eC : e];
        int sD = srt[hD ? eD : e];
        float evA = el2[sA] + er_n; evA = fmaxf(evA, 0.2f * evA);
        float evB = el2[sB] + er_n; evB = fmaxf(evB, 0.2f * evB);
        float evC = el2[sC] + er_n; evC = fmaxf(evC, 0.2f * evC);
        float evD = el2[sD] + er_n; evD = fmaxf(evD, 0.2f * evD);
        float exA = __expf(evA);
        float exB = hB ? __expf(evB) : 0.f;
        float exC = hC ? __expf(evC) : 0.f;
        float exD = hD ? __expf(evD) : 0.f;
        float hA = h2[(size_t)sA * 16 + dim];
        float hBv = h2[(size_t)sB * 16 + dim];
        float hCv = h2[(size_t)sC * 16 + dim];
        float hDv = h2[(size_t)sD * 16 + dim];
        dsum += (exA + exB) + (exC + exD);
        acc += exA * hA + exB * hBv + exC * hCv + exD * hDv;
    }
    acc += __shfl_xor(acc, 16); acc += __shfl_xor(acc, 32);
    dsum += __shfl_xor(dsum, 16); dsum += __shfl_xor(dsum, 32);
    float inv = dsum > 0.f ? 1.f / dsum : 0.f;
    float o = elu_f(acc * inv + b2[dim]);
    if (lane < 16) out[(size_t)node * 16 + dim] = o;
}

extern "C" void kernel_launch(void* const* d_in, const int* in_sizes, int n_in,
                              void* d_out, int out_size, void* d_ws, size_t ws_size,
                              hipStream_t stream) {
    const float* x   = (const float*)d_in[0];
    const int*   src = (const int*)d_in[1];
    const int*   dst = (const int*)d_in[2];
    const float* W1  = (const float*)d_in[3];
    const float* al1 = (const float*)d_in[4];
    const float* ar1 = (const float*)d_in[5];
    const float* b1  = (const float*)d_in[6];
    const float* W2  = (const float*)d_in[7];
    const float* al2 = (const float*)d_in[8];
    const float* ar2 = (const float*)d_in[9];
    const float* b2  = (const float*)d_in[10];
    const int N = in_sizes[0] / 256;
    const int E = in_sizes[1];

    char* wsp = (char*)d_ws;
    size_t off = 0;
    auto alloc = [&](size_t bytes) -> void* {
        void* p = wsp + off;
        off = (off + bytes + 255) & ~(size_t)255;
        return p;
    };
    unsigned short* h1b = (unsigned short*)alloc((size_t)N * 256 * 2);
    unsigned short* x1b = (unsigned short*)alloc((size_t)N * 256 * 2);
    float* el1 = (float*)alloc((size_t)N * 8 * 4);
    float* er1 = (float*)alloc((size_t)N * 8 * 4);
    float* h2  = (float*)alloc((size_t)N * 16 * 4);
    float* el2 = (float*)alloc((size_t)N * 4);
    float* er2 = (float*)alloc((size_t)N * 4);
    int*   offs = (int*)alloc((size_t)(N + 1) * 4);
    int*   srt  = (int*)alloc((size_t)E * 4);
    int2*  ebuf = (int2*)alloc((size_t)E * 8);
    unsigned short* W1t = (unsigned short*)alloc((size_t)272 * 256 * 2);
    unsigned short* W2t = (unsigned short*)alloc((size_t)32 * 256 * 2);

    const int nEB = (E + 2047) / 2048;       // edge blocks (2048 edges each)
    const int nbk = (N + 1023) >> 10;        // buckets (1024 nodes each)
    const int n2  = nbk * nEB;               // flat (bucket, block) count matrix
    const int NB2 = (n2 + 1023) / 1024;      // scan chunks (<= 64)
    const int nGB = (N + 127) / 128;         // gemm1 blocks

    int* cntmat  = (int*)alloc((size_t)n2 * 4);
    int* scanned = (int*)alloc((size_t)(n2 + 1) * 4);
    int* bsum    = (int*)alloc((size_t)64 * 4);

    prep_hist_kernel<<<nEB + 258, 256, 0, stream>>>(dst, cntmat, E, nEB, nbk,
                                                    W1, al1, ar1, W2, al2, ar2, W1t, W2t);
    bsum_kernel<<<NB2, 256, 0, stream>>>(cntmat, bsum, n2);
    scan_final_kernel<<<NB2, 256, 0, stream>>>(cntmat, bsum, scanned, n2, NB2);
    scatter_gemm1_kernel<<<nEB + nGB, 512, 0, stream>>>(src, dst, scanned, ebuf, E, nEB, nbk,
                                                        x, W1t, h1b, el1, er1, N, nGB);
    bucket_csr_kernel<<<nbk, 1024, 0, stream>>>(ebuf, scanned, offs, srt, N, E, nEB, nbk);

    agg1_kernel<<<(N + 3) / 4, 256, 0, stream>>>(h1b, el1, er1, b1, offs, srt, x1b, N);
    gemm2_mfma<<<(N + 63) / 64, 256, 0, stream>>>(x1b, W2t, h2, el2, er2, N);
    agg2_kernel<<<(N + 3) / 4, 256, 0, stream>>>(h2, el2, er2, b2, offs, srt, (float*)d_out, N);
}

// Round 16
// 161.720 us; speedup vs baseline: 1.0759x; 1.0758x over previous
//
#include <hip/hip_runtime.h>
#include <math.h>

typedef __attribute__((ext_vector_type(8))) short short8;
typedef __attribute__((ext_vector_type(4))) float f32x4;

__device__ __forceinline__ float elu_f(float v) {
    return v > 0.f ? v : __expf(v) - 1.f;
}

__device__ __forceinline__ unsigned short f2bf(float f) {
    unsigned u = __float_as_uint(f);
    unsigned r = (u + 0x7FFF + ((u >> 16) & 1)) >> 16;   // round-to-nearest-even
    return (unsigned short)r;
}

__device__ __forceinline__ float bf2f(unsigned short u) {
    return __uint_as_float(((unsigned)u) << 16);
}

// ---------------- weight precompute ----------------
// blocks 0..255: W1t col b; 256: W1t cols 256..271 = [W1.al1 | W1.ar1]; 257: W2t 32 cols
__global__ __launch_bounds__(256) void prep_kernel(const float* __restrict__ W1,
                                                   const float* __restrict__ al1, const float* __restrict__ ar1,
                                                   const float* __restrict__ W2,
                                                   const float* __restrict__ al2, const float* __restrict__ ar2,
                                                   unsigned short* __restrict__ W1t,
                                                   unsigned short* __restrict__ W2t) {
    int b = blockIdx.x, t = threadIdx.x;
    if (b < 256) {
        W1t[b * 256 + t] = f2bf(W1[t * 256 + b]);
    } else if (b == 256) {
        int k = t;
        #pragma unroll
        for (int h = 0; h < 8; h++) {
            float sl = 0.f, sr = 0.f;
            #pragma unroll
            for (int d = 0; d < 32; d++) {
                float wv = W1[k * 256 + 32 * h + d];
                sl += wv * al1[h * 32 + d];
                sr += wv * ar1[h * 32 + d];
            }
            W1t[(256 + h) * 256 + k] = f2bf(sl);
            W1t[(264 + h) * 256 + k] = f2bf(sr);
        }
    } else {
        int k = t;
        float sl = 0.f, sr = 0.f;
        #pragma unroll
        for (int c = 0; c < 16; c++) {
            float wv = W2[k * 16 + c];
            W2t[c * 256 + k] = f2bf(wv);
            sl += wv * al2[c];
            sr += wv * ar2[c];
        }
        W2t[16 * 256 + k] = f2bf(sl);
        W2t[17 * 256 + k] = f2bf(sr);
        #pragma unroll
        for (int c = 18; c < 32; c++) W2t[c * 256 + k] = 0;
    }
}

// ---------------- P1: per-block bucket histogram (bucket = dst >> 10) ----------------
__global__ __launch_bounds__(256) void hist_kernel(const int* __restrict__ dst, int* __restrict__ cntmat,
                                                   int E, int nEB, int nbk) {
    __shared__ int hist[64];
    int b = blockIdx.x, t = threadIdx.x;
    if (t < nbk) hist[t] = 0;
    __syncthreads();
    int e0 = b * 2048 + t * 8;
    #pragma unroll
    for (int i = 0; i < 8; i += 4) {
        int e = e0 + i;
        if (e + 3 < E) {
            int4 d4 = *(const int4*)&dst[e];
            atomicAdd(&hist[d4.x >> 10], 1);
            atomicAdd(&hist[d4.y >> 10], 1);
            atomicAdd(&hist[d4.z >> 10], 1);
            atomicAdd(&hist[d4.w >> 10], 1);
        } else {
            for (int ee = e; ee < E && ee < e + 4; ee++) atomicAdd(&hist[dst[ee] >> 10], 1);
        }
    }
    __syncthreads();
    if (t < nbk) cntmat[t * nEB + b] = hist[t];   // bucket-major layout for flat scan
}

// per-1024-chunk sums (generic flat scan, n arbitrary)
__global__ __launch_bounds__(256) void bsum_kernel(const int* __restrict__ cnt, int* __restrict__ bsum, int n) {
    int b = blockIdx.x, t = threadIdx.x;
    int i0 = b * 1024 + t * 4;
    int s = 0;
    #pragma unroll
    for (int k = 0; k < 4; k++) { int i = i0 + k; if (i < n) s += cnt[i]; }
    #pragma unroll
    for (int m = 1; m < 64; m <<= 1) s += __shfl_xor(s, m);
    __shared__ int ws[4];
    if ((t & 63) == 0) ws[t >> 6] = s;
    __syncthreads();
    if (t == 0) bsum[b] = ws[0] + ws[1] + ws[2] + ws[3];
}

// rescan each 1024-chunk; block-sum prefix recomputed locally (nb <= 64); writes offs[0..n]
__global__ __launch_bounds__(256) void scan_final_kernel(const int* __restrict__ cnt, const int* __restrict__ bsum,
                                                         int* __restrict__ offs, int n, int nb) {
    int b = blockIdx.x, t = threadIdx.x, lane = t & 63, w = t >> 6;
    __shared__ int ws[4];
    __shared__ int bbase_s;
    int i0 = b * 1024 + t * 4;
    int v[4]; int ts = 0;
    #pragma unroll
    for (int k = 0; k < 4; k++) { int i = i0 + k; v[k] = (i < n) ? cnt[i] : 0; ts += v[k]; }
    int x = ts;
    #pragma unroll
    for (int off = 1; off < 64; off <<= 1) {
        int y = __shfl_up(x, off);
        if (lane >= off) x += y;
    }
    if (lane == 63) ws[w] = x;
    if (w == 0) {
        int bv = (lane < nb) ? bsum[lane] : 0;
        int bx = bv;
        #pragma unroll
        for (int off = 1; off < 64; off <<= 1) {
            int y = __shfl_up(bx, off);
            if (lane >= off) bx += y;
        }
        if (lane == b) bbase_s = bx - bv;
    }
    __syncthreads();
    int wbase = 0;
    #pragma unroll
    for (int k = 0; k < 4; k++) if (k < w) wbase += ws[k];
    int base = bbase_s + wbase + (x - ts);
    #pragma unroll
    for (int k = 0; k < 4; k++) {
        int i = i0 + k;
        if (i < n) offs[i] = base;
        base += v[k];
        if (i == n - 1) offs[n] = base;
    }
}

// ---------------- P3: bucket scatter (LDS rank, no global atomics) ----------------
__global__ __launch_bounds__(256) void bucket_scatter_kernel(const int* __restrict__ src,
                                                             const int* __restrict__ dst,
                                                             const int* __restrict__ scanned,
                                                             int2* __restrict__ ebuf,
                                                             int E, int nEB, int nbk) {
    __shared__ int sb[64];
    __shared__ int cur[64];
    int b = blockIdx.x, t = threadIdx.x;
    if (t < nbk) { sb[t] = scanned[t * nEB + b]; cur[t] = 0; }
    __syncthreads();
    int e0 = b * 2048 + t * 8;
    #pragma unroll
    for (int i = 0; i < 8; i += 4) {
        int e = e0 + i;
        if (e + 3 < E) {
            int4 d4 = *(const int4*)&dst[e];
            int4 s4 = *(const int4*)&src[e];
            int k, r;
            k = d4.x >> 10; r = atomicAdd(&cur[k], 1); ebuf[sb[k] + r] = make_int2(d4.x, s4.x);
            k = d4.y >> 10; r = atomicAdd(&cur[k], 1); ebuf[sb[k] + r] = make_int2(d4.y, s4.y);
            k = d4.z >> 10; r = atomicAdd(&cur[k], 1); ebuf[sb[k] + r] = make_int2(d4.z, s4.z);
            k = d4.w >> 10; r = atomicAdd(&cur[k], 1); ebuf[sb[k] + r] = make_int2(d4.w, s4.w);
        } else {
            for (int ee = e; ee < E && ee < e + 4; ee++) {
                int d = dst[ee];
                int k = d >> 10;
                int r = atomicAdd(&cur[k], 1);
                ebuf[sb[k] + r] = make_int2(d, src[ee]);
            }
        }
    }
}

// ---------------- P4: per-bucket CSR finalize (LDS count + scan + cursor scatter) ----------------
__global__ __launch_bounds__(1024) void bucket_csr_kernel(const int2* __restrict__ ebuf,
                                                          const int* __restrict__ scanned,
                                                          int* __restrict__ offs, int* __restrict__ srt,
                                                          int N, int E, int nEB, int nbk) {
    __shared__ int lcnt[1024];
    __shared__ int lcur[1024];
    __shared__ int ws[16];
    int k = blockIdx.x, t = threadIdx.x;
    int lane = t & 63, w = t >> 6;
    int eb = scanned[k * nEB];
    int ee = (k + 1 < nbk) ? scanned[(k + 1) * nEB] : E;
    lcnt[t] = 0;
    __syncthreads();
    for (int e = eb + t; e < ee; e += 1024) {
        int2 p = ebuf[e];
        atomicAdd(&lcnt[p.x & 1023], 1);
    }
    __syncthreads();
    int v = lcnt[t];
    int x = v;
    #pragma unroll
    for (int off = 1; off < 64; off <<= 1) {
        int y = __shfl_up(x, off);
        if (lane >= off) x += y;
    }
    if (lane == 63) ws[w] = x;
    __syncthreads();
    if (w == 0) {
        int wv = (lane < 16) ? ws[lane] : 0;
        int wx = wv;
        #pragma unroll
        for (int off = 1; off < 16; off <<= 1) {
            int y = __shfl_up(wx, off);
            if (lane >= off) wx += y;
        }
        if (lane < 16) ws[lane] = wx - wv;   // exclusive wave bases
    }
    __syncthreads();
    int excl = ws[w] + (x - v);
    int node = (k << 10) + t;
    if (node < N) offs[node] = eb + excl;
    if (k == nbk - 1 && t == 0) offs[N] = E;
    lcur[t] = eb + excl;
    __syncthreads();
    for (int e = eb + t; e < ee; e += 1024) {
        int2 p = ebuf[e];
        int pos = atomicAdd(&lcur[p.x & 1023], 1);
        srt[pos] = p.y;
    }
}

// ---------------- GEMM1: [h1 | el1 | er1] = x @ [W1 | wl | wr] via bf16 MFMA ----------------
#define STR1 40
__global__ __launch_bounds__(512) void gemm1_mfma(const float* __restrict__ x,
                                                  const unsigned short* __restrict__ W1t,
                                                  unsigned short* __restrict__ h,
                                                  float* __restrict__ el1, float* __restrict__ er1, int n) {
    __shared__ unsigned short As[128 * STR1];
    __shared__ unsigned short Bs[272 * STR1];
    int t = threadIdx.x;
    int w = t >> 6, l = t & 63;
    int rb = blockIdx.x * 128;
    f32x4 acc[17] = {};
    int ar = t >> 2;          // A-stage row 0..127
    int ak = (t & 3) * 8;     // A-stage k0
    int lr = w * 16 + (l & 15);
    int lg = l >> 4;
    for (int kc = 0; kc < 256; kc += 32) {
        {   // stage A (128x32), fp32 -> bf16
            int gr = rb + ar;
            float v[8];
            if (gr < n) {
                f32x4 v0 = *(const f32x4*)&x[(size_t)gr * 256 + kc + ak];
                f32x4 v1 = *(const f32x4*)&x[(size_t)gr * 256 + kc + ak + 4];
                v[0] = v0.x; v[1] = v0.y; v[2] = v0.z; v[3] = v0.w;
                v[4] = v1.x; v[5] = v1.y; v[6] = v1.z; v[7] = v1.w;
            } else {
                #pragma unroll
                for (int i = 0; i < 8; i++) v[i] = 0.f;
            }
            short8 bv;
            #pragma unroll
            for (int i = 0; i < 8; i++) bv[i] = (short)f2bf(v[i]);
            *(short8*)&As[ar * STR1 + ak] = bv;
        }
        #pragma unroll
        for (int i = 0; i < 3; i++) {   // stage B: 272 cols x 4 chunks = 1088
            int idx = t + i * 512;
            if (idx < 1088) {
                int bn = idx >> 2;
                int bk = (idx & 3) * 8;
                short8 bv = *(const short8*)&W1t[(size_t)bn * 256 + kc + bk];
                *(short8*)&Bs[bn * STR1 + bk] = bv;
            }
        }
        __syncthreads();
        short8 a = *(short8*)&As[lr * STR1 + lg * 8];
        #pragma unroll
        for (int j = 0; j < 17; j++) {
            short8 bfrag = *(short8*)&Bs[(j * 16 + (l & 15)) * STR1 + lg * 8];
            acc[j] = __builtin_amdgcn_mfma_f32_16x16x32_bf16(a, bfrag, acc[j], 0, 0, 0);
        }
        __syncthreads();
    }
    int r0 = rb + w * 16 + 4 * (l >> 4);
    int c0 = l & 15;
    #pragma unroll
    for (int j = 0; j < 16; j++) {
        #pragma unroll
        for (int i = 0; i < 4; i++) {
            int gr = r0 + i;
            if (gr < n) h[(size_t)gr * 256 + j * 16 + c0] = f2bf(acc[j][i]);
        }
    }
    #pragma unroll
    for (int i = 0; i < 4; i++) {       // j=16: cols 256..271 = [el(8) | er(8)]
        int gr = r0 + i;
        if (gr < n) {
            if (c0 < 8) el1[gr * 8 + c0] = acc[16][i];
            else        er1[gr * 8 + (c0 - 8)] = acc[16][i];
        }
    }
}

// ---------------- layer-1 aggregation + bias + ELU -> x1 (bf16) ----------------
__global__ __launch_bounds__(256) void agg1_kernel(const unsigned short* __restrict__ h1b,
                                                   const float* __restrict__ el1,
                                                   const float* __restrict__ er1, const float* __restrict__ b1,
                                                   const int* __restrict__ offs, const int* __restrict__ srt,
                                                   unsigned short* __restrict__ x1b, int n) {
    int t = threadIdx.x; int lane = t & 63;
    int node = blockIdx.x * 4 + (t >> 6);
    if (node >= n) return;
    int beg = offs[node], end = offs[node + 1];
    int q = lane & 31;          // dim-group: dims [8q, 8q+8)
    int head = q >> 2;
    int half = lane >> 5;
    float er_h = er1[node * 8 + head];
    float acc[8] = {};
    float dsum = 0.f;
    for (int e = beg + half; e < end; e += 8) {
        int eB = e + 2, eC = e + 4, eD = e + 6;
        bool hB = eB < end, hC = eC < end, hD = eD < end;
        int sA = srt[e];
        int sB = srt[hB ? eB : e];
        int sC = srt[hC ? eC : e];
        int sD = srt[hD ? eD : e];
        float exA = __expf(el1[sA * 8 + head] + er_h);          // leaky slope 1.0 == identity
        float exB = hB ? __expf(el1[sB * 8 + head] + er_h) : 0.f;
        float exC = hC ? __expf(el1[sC * 8 + head] + er_h) : 0.f;
        float exD = hD ? __expf(el1[sD * 8 + head] + er_h) : 0.f;
        short8 hA = *(const short8*)&h1b[(size_t)sA * 256 + q * 8];
        short8 hBv = *(const short8*)&h1b[(size_t)sB * 256 + q * 8];
        short8 hCv = *(const short8*)&h1b[(size_t)sC * 256 + q * 8];
        short8 hDv = *(const short8*)&h1b[(size_t)sD * 256 + q * 8];
        dsum += (exA + exB) + (exC + exD);
        #pragma unroll
        for (int k = 0; k < 8; k++)
            acc[k] += exA * bf2f((unsigned short)hA[k]) + exB * bf2f((unsigned short)hBv[k])
                    + exC * bf2f((unsigned short)hCv[k]) + exD * bf2f((unsigned short)hDv[k]);
    }
    dsum += __shfl_xor(dsum, 32);
    #pragma unroll
    for (int k = 0; k < 8; k++) acc[k] += __shfl_xor(acc[k], 32);
    if (half == 0) {
        float inv = dsum > 0.f ? 1.f / dsum : 0.f;
        f32x4 b0 = *(const f32x4*)&b1[q * 8];
        f32x4 b4 = *(const f32x4*)&b1[q * 8 + 4];
        float o[8];
        o[0] = elu_f(acc[0] * inv + b0.x); o[1] = elu_f(acc[1] * inv + b0.y);
        o[2] = elu_f(acc[2] * inv + b0.z); o[3] = elu_f(acc[3] * inv + b0.w);
        o[4] = elu_f(acc[4] * inv + b4.x); o[5] = elu_f(acc[5] * inv + b4.y);
        o[6] = elu_f(acc[6] * inv + b4.z); o[7] = elu_f(acc[7] * inv + b4.w);
        short8 ov;
        #pragma unroll
        for (int k = 0; k < 8; k++) ov[k] = (short)f2bf(o[k]);
        *(short8*)&x1b[(size_t)node * 256 + q * 8] = ov;
    }
}

// ---------------- GEMM2: [h2 | el2 | er2] = x1 @ [W2 | wl2 | wr2] via bf16 MFMA; h2 fp32 ----------------
__global__ __launch_bounds__(256) void gemm2_mfma(const unsigned short* __restrict__ x1b,
                                                  const unsigned short* __restrict__ W2t,
                                                  float* __restrict__ h2, float* __restrict__ el2,
                                                  float* __restrict__ er2, int n) {
    __shared__ unsigned short As[64 * STR1];
    __shared__ unsigned short Bs[32 * STR1];
    int t = threadIdx.x;
    int w = t >> 6, l = t & 63;
    int rb = blockIdx.x * 64;
    f32x4 acc[2] = {};
    int ar = t >> 2;
    int ak = (t & 3) * 8;
    int lr = w * 16 + (l & 15);
    int lg = l >> 4;
    for (int kc = 0; kc < 256; kc += 32) {
        {
            int gr = rb + ar;
            short8 av = {0, 0, 0, 0, 0, 0, 0, 0};
            if (gr < n) av = *(const short8*)&x1b[(size_t)gr * 256 + kc + ak];
            *(short8*)&As[ar * STR1 + ak] = av;
        }
        if (t < 128) {   // 32 cols x 4 chunks
            int bn = t >> 2, bk = (t & 3) * 8;
            short8 bv = *(const short8*)&W2t[(size_t)bn * 256 + kc + bk];
            *(short8*)&Bs[bn * STR1 + bk] = bv;
        }
        __syncthreads();
        short8 a = *(short8*)&As[lr * STR1 + lg * 8];
        #pragma unroll
        for (int j = 0; j < 2; j++) {
            short8 bfrag = *(short8*)&Bs[(j * 16 + (l & 15)) * STR1 + lg * 8];
            acc[j] = __builtin_amdgcn_mfma_f32_16x16x32_bf16(a, bfrag, acc[j], 0, 0, 0);
        }
        __syncthreads();
    }
    int r0 = rb + w * 16 + 4 * (l >> 4);
    int c0 = l & 15;
    #pragma unroll
    for (int i = 0; i < 4; i++) {
        int gr = r0 + i;
        if (gr < n) {
            h2[(size_t)gr * 16 + c0] = acc[0][i];
            if (c0 == 0) el2[gr] = acc[1][i];        // col 16
            else if (c0 == 1) er2[gr] = acc[1][i];   // col 17
        }
    }
}

// ---------------- layer-2 aggregation + bias + ELU -> out ----------------
__global__ __launch_bounds__(256) void agg2_kernel(const float* __restrict__ h2,
                                                   const float* __restrict__ el2,
                                                   const float* __restrict__ er2, const float* __restrict__ b2,
                                                   const int* __restrict__ offs, const int* __restrict__ srt,
                                                   float* __restrict__ out, int n) {
    int t = threadIdx.x; int lane = t & 63;
    int node = blockIdx.x * 4 + (t >> 6);
    if (node >= n) return;
    int beg = offs[node], end = offs[node + 1];
    int dim = lane & 15, eg = lane >> 4;
    float er_n = er2[node];
    float acc = 0.f, dsum = 0.f;
    for (int e = beg + eg; e < end; e += 16) {
        int eB = e + 4, eC = e + 8, eD = e + 12;
        bool hB = eB < end, hC = eC < end, hD = eD < end;
        int sA = srt[e];
        int sB = srt[hB ? eB : e];
        int sC = srt[hC ? eC : e];
        int sD = srt[hD ? eD : e];
        float evA = el2[sA] + er_n; evA = fmaxf(evA, 0.2f * evA);
        float evB = el2[sB] + er_n; evB = fmaxf(evB, 0.2f * evB);
        float evC = el2[sC] + er_n; evC = fmaxf(evC, 0.2f * evC);
        float evD = el2[sD] + er_n; evD = fmaxf(evD, 0.2f * evD);
        float exA = __expf(evA);
        float exB = hB ? __expf(evB) : 0.f;
        float exC = hC ? __expf(evC) : 0.f;
        float exD = hD ? __expf(evD) : 0.f;
        float hA = h2[(size_t)sA * 16 + dim];
        float hBv = h2[(size_t)sB * 16 + dim];
        float hCv = h2[(size_t)sC * 16 + dim];
        float hDv = h2[(size_t)sD * 16 + dim];
        dsum += (exA + exB) + (exC + exD);
        acc += exA * hA + exB * hBv + exC * hCv + exD * hDv;
    }
    acc += __shfl_xor(acc, 16); acc += __shfl_xor(acc, 32);
    dsum += __shfl_xor(dsum, 16); dsum += __shfl_xor(dsum, 32);
    float inv = dsum > 0.f ? 1.f / dsum : 0.f;
    float o = elu_f(acc * inv + b2[dim]);
    if (lane < 16) out[(size_t)node * 16 + dim] = o;
}

extern "C" void kernel_launch(void* const* d_in, const int* in_sizes, int n_in,
                              void* d_out, int out_size, void* d_ws, size_t ws_size,
                              hipStream_t stream) {
    const float* x   = (const float*)d_in[0];
    const int*   src = (const int*)d_in[1];
    const int*   dst = (const int*)d_in[2];
    const float* W1  = (const float*)d_in[3];
    const float* al1 = (const float*)d_in[4];
    const float* ar1 = (const float*)d_in[5];
    const float* b1  = (const float*)d_in[6];
    const float* W2  = (const float*)d_in[7];
    const float* al2 = (const float*)d_in[8];
    const float* ar2 = (const float*)d_in[9];
    const float* b2  = (const float*)d_in[10];
    const int N = in_sizes[0] / 256;
    const int E = in_sizes[1];

    char* wsp = (char*)d_ws;
    size_t off = 0;
    auto alloc = [&](size_t bytes) -> void* {
        void* p = wsp + off;
        off = (off + bytes + 255) & ~(size_t)255;
        return p;
    };
    unsigned short* h1b = (unsigned short*)alloc((size_t)N * 256 * 2);
    unsigned short* x1b = (unsigned short*)alloc((size_t)N * 256 * 2);
    float* el1 = (float*)alloc((size_t)N * 8 * 4);
    float* er1 = (float*)alloc((size_t)N * 8 * 4);
    float* h2  = (float*)alloc((size_t)N * 16 * 4);
    float* el2 = (float*)alloc((size_t)N * 4);
    float* er2 = (float*)alloc((size_t)N * 4);
    int*   offs = (int*)alloc((size_t)(N + 1) * 4);
    int*   srt  = (int*)alloc((size_t)E * 4);
    int2*  ebuf = (int2*)alloc((size_t)E * 8);
    unsigned short* W1t = (unsigned short*)alloc((size_t)272 * 256 * 2);
    unsigned short* W2t = (unsigned short*)alloc((size_t)32 * 256 * 2);

    const int nEB = (E + 2047) / 2048;       // edge blocks (2048 edges each)
    const int nbk = (N + 1023) >> 10;        // buckets (1024 nodes each)
    const int n2  = nbk * nEB;               // flat (bucket, block) count matrix
    const int NB2 = (n2 + 1023) / 1024;      // scan chunks (<= 64)

    int* cntmat  = (int*)alloc((size_t)n2 * 4);
    int* scanned = (int*)alloc((size_t)(n2 + 1) * 4);
    int* bsum    = (int*)alloc((size_t)64 * 4);

    prep_kernel<<<258, 256, 0, stream>>>(W1, al1, ar1, W2, al2, ar2, W1t, W2t);
    hist_kernel<<<nEB, 256, 0, stream>>>(dst, cntmat, E, nEB, nbk);
    bsum_kernel<<<NB2, 256, 0, stream>>>(cntmat, bsum, n2);
    scan_final_kernel<<<NB2, 256, 0, stream>>>(cntmat, bsum, scanned, n2, NB2);
    bucket_scatter_kernel<<<nEB, 256, 0, stream>>>(src, dst, scanned, ebuf, E, nEB, nbk);
    bucket_csr_kernel<<<nbk, 1024, 0, stream>>>(ebuf, scanned, offs, srt, N, E, nEB, nbk);

    gemm1_mfma<<<(N + 127) / 128, 512, 0, stream>>>(x, W1t, h1b, el1, er1, N);
    agg1_kernel<<<(N + 3) / 4, 256, 0, stream>>>(h1b, el1, er1, b1, offs, srt, x1b, N);
    gemm2_mfma<<<(N + 63) / 64, 256, 0, stream>>>(x1b, W2t, h2, el2, er2, N);
    agg2_kernel<<<(N + 3) / 4, 256, 0, stream>>>(h2, el2, er2, b2, offs, srt, (float*)d_out, N);
}